// Round 4
// baseline (335.547 us; speedup 1.0000x reference)
//
#include <hip/hip_runtime.h>
#include <hip/hip_bf16.h>
#include <stdint.h>

// B=8 L=8192 C=384 DIN=128 HID=512, tokens=65536, bands(16 tok)=4096.
// softmax over size-1 axis == 1 -> attention out == v -> fold Wc = Wv@Wp.
// z = y + gelu(LN2(y)@W1+bm1)@W2 + bm2,  y = LN1(x)@Wc + bc.
// R9: FUSE k1+k2a+k2b. Key fact: lb/ybuf were wave-private (band-local) in
// k2 -> the 3-kernel split pushed wave-private data through ~118MB of global
// round-trips. Now: y lives in yacc regs end-to-end, zacc accumulates both
// MLP halves, y->A-frag layout permutation bounces through the per-wave A3s
// LDS scratch (512-short chunk per ks, index algebra identical to the old
// lb write/read pair). LDS union buffer restaged WcT -> W1a/W2a -> W1b/W2b
// (159232 B static). Traffic: read x 100MB + weights, write out 33.5MB, no
// intermediates. Also numerically better (no double bf16 rounding of y).

typedef __attribute__((ext_vector_type(8))) short bf16x8;
typedef __attribute__((ext_vector_type(4))) float f32x4;

__device__ __forceinline__ short f2bf(float f) {
  union { float f; unsigned u; } a; a.f = f;
  unsigned u = a.u;
  u += 0x7fffu + ((u >> 16) & 1u);   // RNE, finite inputs
  return (short)(u >> 16);
}
__device__ __forceinline__ float bf2f(short s) {
  union { unsigned u; float f; } a; a.u = ((unsigned)(unsigned short)s) << 16;
  return a.f;
}
__device__ __forceinline__ float gelu_fast(float h) {
  // 0.5h(1+tanh(u)) = h*sigmoid(2u); 2u*log2e = h*(2.3022082+0.1029471h^2)
  float h2 = h * h;
  float w  = h * (2.3022082f + 0.1029471f * h2);
  float e  = __builtin_amdgcn_exp2f(w);
  float r  = __builtin_amdgcn_rcpf(e + 1.0f);
  return h - h * r;
}
__device__ __forceinline__ void gload_lds16(const void* g, void* l) {
  __builtin_amdgcn_global_load_lds(
      (const __attribute__((address_space(1))) unsigned*)g,
      (__attribute__((address_space(3))) unsigned*)l, 16, 0, 0);
}

// ws layout:
//   WcT  [128][392] @0         (100352)  col n, k-major; = g1[k]*Wc[k][n] bf16
//   W1Ta [256][132] @100352    (67584)   W1[k][n]*g2[k], n<256
//   W2Ta [4][128][68] @167936  (69632)
//   W1Tb [256][132] @237568    (67584)
//   W2Tb [4][128][68] @305152  (69632)
//   bc   [128]f32  @374784     bp + (bkv_v + b1@Wv)@Wp
//   bm1c [512]f32  @375296     bm1 + b2@W1

// ---------------- prep (707 blocks x 256) ------------------------------------
__global__ void prep(const float* __restrict__ Wkv, const float* __restrict__ bkv,
                     const float* __restrict__ Wp,  const float* __restrict__ bp,
                     const float* __restrict__ W1,  const float* __restrict__ W2,
                     const float* __restrict__ g1,  const float* __restrict__ b1,
                     const float* __restrict__ g2,  const float* __restrict__ b2,
                     const float* __restrict__ bm1,
                     short* __restrict__ WcT, short* __restrict__ W1Ta,
                     short* __restrict__ W1Tb, short* __restrict__ W2Ta,
                     short* __restrict__ W2Tb, float* __restrict__ bc,
                     float* __restrict__ bm1c) {
  const int b = blockIdx.x, tid = threadIdx.x;
  if (b < 192) {                        // WcT fold + g1 scale
    __shared__ float wv[2][128];
    const int kk = tid >> 7, n = tid & 127, k = 2 * b + kk;
    wv[kk][n] = Wkv[k * 256 + 128 + n];
    __syncthreads();
    float s0 = 0, s1 = 0, s2 = 0, s3 = 0;
#pragma unroll 8
    for (int m = 0; m < 128; m += 4) {
      s0 += wv[kk][m]     * Wp[(m)     * 128 + n];
      s1 += wv[kk][m + 1] * Wp[(m + 1) * 128 + n];
      s2 += wv[kk][m + 2] * Wp[(m + 2) * 128 + n];
      s3 += wv[kk][m + 3] * Wp[(m + 3) * 128 + n];
    }
    WcT[n * 392 + k] = f2bf(g1[k] * (s0 + s1 + s2 + s3));
  } else if (b == 192) {                // bc = bp + (bkv_v + b1@Wv)@Wp
    __shared__ float t[128];
    if (tid < 128) {
      float a0 = 0, a1 = 0, a2 = 0, a3 = 0;
#pragma unroll 8
      for (int k = 0; k < 384; k += 4) {
        a0 += b1[k]     * Wkv[(k)     * 256 + 128 + tid];
        a1 += b1[k + 1] * Wkv[(k + 1) * 256 + 128 + tid];
        a2 += b1[k + 2] * Wkv[(k + 2) * 256 + 128 + tid];
        a3 += b1[k + 3] * Wkv[(k + 3) * 256 + 128 + tid];
      }
      t[tid] = a0 + a1 + a2 + a3 + bkv[128 + tid];
    }
    __syncthreads();
    if (tid < 128) {
      float s = bp[tid];
#pragma unroll 8
      for (int m = 0; m < 128; ++m) s += t[m] * Wp[m * 128 + tid];
      bc[tid] = s;
    }
  } else if (b < 449) {                 // W1T halves, rows scaled by g2[k]
    const int id = (b - 193) * 256 + tid;
    const int n = id & 511, k = id >> 9;
    const short v = f2bf(W1[k * 512 + n] * g2[k]);
    if (n < 256) W1Ta[n * 132 + k] = v;
    else         W1Tb[(n - 256) * 132 + k] = v;
  } else if (b < 705) {                 // W2T, ch-chunked halves
    const int id = (b - 449) * 256 + tid;
    const int n = id & 127, k = id >> 7;
    const int ch = k >> 6, kk = k & 63;
    short* dst = (ch < 4) ? W2Ta : W2Tb;
    dst[((ch & 3) * 128 + n) * 68 + kk] = f2bf(W2[k * 128 + n]);
  } else {                              // bm1c = bm1 + b2@W1
    const int h = (b - 705) * 256 + tid;   // [0,512)
    float s = bm1[h];
#pragma unroll 8
    for (int k = 0; k < 128; ++k) s += b2[k] * W1[k * 512 + h];
    bm1c[h] = s;
  }
}

// ---------------- fused: LN1@Wc + LN2 + MLP, one pass, 16 waves/block --------
__global__ __launch_bounds__(1024)
void fused(const float* __restrict__ x, const short* __restrict__ WcTg,
           const float* __restrict__ bcg,
           const short* __restrict__ W1Tag, const short* __restrict__ W2Tag,
           const short* __restrict__ W1Tbg, const short* __restrict__ W2Tbg,
           const float* __restrict__ bm1c, const float* __restrict__ bm2,
           float* __restrict__ out) {
  // union weight buffer: phase1 WcT[128*392]s (100352B);
  // phase2 W1s[256*132]s @0 (67584B) + W2s[4*128*68]s @67584 (69632B)
  __shared__ __align__(16) char Wbuf[137216];
  __shared__ __align__(16) short A3s[16][576];   // per-wave scratch (1152B)
  __shared__ float bcf[128], css[128], bm1s[512], bm2s[128];
  const int tid = threadIdx.x, lane = tid & 63, w = tid >> 6;
  const int q = lane >> 4, c16 = lane & 15;

  // ---- stage WcT + all bias vectors
  for (int c = w; c < 98; c += 16)
    gload_lds16((const char*)WcTg + c * 1024 + lane * 16, Wbuf + c * 1024);
  if (tid < 128)      ((float4*)bm1s)[tid]       = ((const float4*)bm1c)[tid];
  else if (tid < 160) ((float4*)bm2s)[tid - 128] = ((const float4*)bm2)[tid - 128];
  else if (tid < 192) ((float4*)bcf)[tid - 160]  = ((const float4*)bcg)[tid - 160];
  __syncthreads();
  const short* WcT_l = (const short*)Wbuf;
  if (tid < 128) {                     // colsum of the exact bf16 weights used
    float s0 = 0, s1 = 0, s2 = 0, s3 = 0;
    const short* row = WcT_l + tid * 392;
#pragma unroll 12
    for (int k = 0; k < 384; k += 4) {
      s0 += bf2f(row[k]); s1 += bf2f(row[k + 1]);
      s2 += bf2f(row[k + 2]); s3 += bf2f(row[k + 3]);
    }
    css[tid] = s0 + s1 + s2 + s3;
  }
  __syncthreads();

  // ---- phase 1: y = LN1(x)@Wc + bc via linearity, x streamed once
  const long band = (long)blockIdx.x * 16 + w;
  const float* xp = x + (band * 16 + c16) * 384 + q * 8;
  f32x4 yacc[8];
#pragma unroll
  for (int t = 0; t < 8; ++t) yacc[t] = (f32x4){0.f, 0.f, 0.f, 0.f};
  float s = 0.f, sq = 0.f;
#pragma unroll
  for (int ks = 0; ks < 12; ++ks) {
    const float4 va = *(const float4*)(xp + ks * 32);
    const float4 vb = *(const float4*)(xp + ks * 32 + 4);
    s  += va.x + va.y + va.z + va.w + vb.x + vb.y + vb.z + vb.w;
    sq += va.x * va.x + va.y * va.y + va.z * va.z + va.w * va.w
        + vb.x * vb.x + vb.y * vb.y + vb.z * vb.z + vb.w * vb.w;
    bf16x8 f;
    f[0] = f2bf(va.x); f[1] = f2bf(va.y); f[2] = f2bf(va.z); f[3] = f2bf(va.w);
    f[4] = f2bf(vb.x); f[5] = f2bf(vb.y); f[6] = f2bf(vb.z); f[7] = f2bf(vb.w);
#pragma unroll
    for (int t = 0; t < 8; ++t) {
      bf16x8 bfr = *(const bf16x8*)(WcT_l + (t * 16 + c16) * 392 + ks * 32 + q * 8);
      yacc[t] = __builtin_amdgcn_mfma_f32_16x16x32_bf16(f, bfr, yacc[t], 0, 0, 0);
    }
  }
  // LN1 stats (register-only; done before the barrier that frees Wbuf)
  s  += __shfl_xor(s, 16);  s  += __shfl_xor(s, 32);
  sq += __shfl_xor(sq, 16); sq += __shfl_xor(sq, 32);
  const float mean = s * (1.f / 384.f);
  const float rs = rsqrtf(sq * (1.f / 384.f) - mean * mean + 1e-5f);
  float mr[4], rr[4];
#pragma unroll
  for (int r = 0; r < 4; ++r) {
    mr[r] = __shfl(mean, q * 4 + r);
    rr[r] = __shfl(rs,   q * 4 + r);
  }
  __syncthreads();                      // all waves done reading WcT from Wbuf

  // ---- issue half-a weight staging; overlap with finalize below
  for (int c = w; c < 66; c += 16)
    gload_lds16((const char*)W1Tag + c * 1024 + lane * 16, Wbuf + c * 1024);
  for (int c = w; c < 68; c += 16)
    gload_lds16((const char*)W2Tag + c * 1024 + lane * 16, Wbuf + 67584 + c * 1024);

  // ---- finalize y = rr*(u - mr*colsum) + bc; LN2 stats
  float sm[4] = {0, 0, 0, 0}, sv[4] = {0, 0, 0, 0};
#pragma unroll
  for (int t = 0; t < 8; ++t) {
    const float cst = css[t * 16 + c16];
    const float bct = bcf[t * 16 + c16];
#pragma unroll
    for (int r = 0; r < 4; ++r) {
      const float yv = rr[r] * (yacc[t][r] - mr[r] * cst) + bct;
      yacc[t][r] = yv; sm[r] += yv; sv[r] += yv * yv;
    }
  }
#pragma unroll
  for (int r = 0; r < 4; ++r) {
    sm[r] += __shfl_xor(sm[r], 1); sm[r] += __shfl_xor(sm[r], 2);
    sm[r] += __shfl_xor(sm[r], 4); sm[r] += __shfl_xor(sm[r], 8);
    sv[r] += __shfl_xor(sv[r], 1); sv[r] += __shfl_xor(sv[r], 2);
    sv[r] += __shfl_xor(sv[r], 4); sv[r] += __shfl_xor(sv[r], 8);
  }
  float mn[4], rv[4];
#pragma unroll
  for (int r = 0; r < 4; ++r) {
    mn[r] = sm[r] * (1.f / 128.f);
    rv[r] = rsqrtf(sv[r] * (1.f / 128.f) - mn[r] * mn[r] + 1e-5f);
  }

  // ---- bounce y-norm (g2/b2 folded) -> A-fragments via per-wave LDS chunk.
  // old lb idx = t*256 + r*64 + q*16 + c16 (write) and
  //              t*256 + (c16&3)*64 + (c16>>2)*16 + (q&1)*8 (read, t=2ks+(q>>1));
  // chunk ks = idx in [ks*512, ks*512+512) -> fits the 576-short A3s scratch.
  short* A3w = A3s[w];
  bf16x8 a2f[4];
#pragma unroll
  for (int ks = 0; ks < 4; ++ks) {
#pragma unroll
    for (int tt = 0; tt < 2; ++tt) {
      const int t = ks * 2 + tt;
#pragma unroll
      for (int r = 0; r < 4; ++r)
        A3w[tt * 256 + r * 64 + q * 16 + c16] = f2bf((yacc[t][r] - mn[r]) * rv[r]);
    }
    asm volatile("s_waitcnt lgkmcnt(0)" ::: "memory");  // in-wave RAW
    a2f[ks] = *(const bf16x8*)(A3w + (q >> 1) * 256 + (c16 & 3) * 64 +
                               (c16 >> 2) * 16 + (q & 1) * 8);
  }

  // ---- phase 2: MLP, both hidden halves, zacc accumulates in regs
  f32x4 zacc[8];
#pragma unroll
  for (int t = 0; t < 8; ++t) zacc[t] = (f32x4){0.f, 0.f, 0.f, 0.f};
  const short* W1s = (const short*)Wbuf;
  const short* W2s = (const short*)(Wbuf + 67584);

  for (int half = 0; half < 2; ++half) {
    if (half) {
      __syncthreads();                  // all waves done with half-a weights
      for (int c = w; c < 66; c += 16)
        gload_lds16((const char*)W1Tbg + c * 1024 + lane * 16, Wbuf + c * 1024);
      for (int c = w; c < 68; c += 16)
        gload_lds16((const char*)W2Tbg + c * 1024 + lane * 16, Wbuf + 67584 + c * 1024);
    }
    __syncthreads();                    // drains vmcnt -> stage complete

#pragma unroll
    for (int ch = 0; ch < 4; ++ch) {
#pragma unroll
      for (int sub = 0; sub < 2; ++sub) {
        f32x4 hacc[2];
        hacc[0] = (f32x4){0.f, 0.f, 0.f, 0.f};
        hacc[1] = (f32x4){0.f, 0.f, 0.f, 0.f};
#pragma unroll
        for (int ks = 0; ks < 4; ++ks)
#pragma unroll
          for (int tt = 0; tt < 2; ++tt) {
            bf16x8 bfr = *(const bf16x8*)(W1s + (ch * 64 + sub * 32 + tt * 16 + c16) * 132 + ks * 32 + q * 8);
            hacc[tt] = __builtin_amdgcn_mfma_f32_16x16x32_bf16(a2f[ks], bfr, hacc[tt], 0, 0, 0);
          }
#pragma unroll
        for (int tt = 0; tt < 2; ++tt) {
          const float bb = bm1s[half * 256 + ch * 64 + sub * 32 + tt * 16 + c16];
#pragma unroll
          for (int r = 0; r < 4; ++r) {
            const float h = hacc[tt][r] + bb;
            A3w[(q * 4 + r) * 36 + tt * 16 + c16] = f2bf(gelu_fast(h));
          }
        }
        asm volatile("s_waitcnt lgkmcnt(0)" ::: "memory");  // in-wave A3 RAW
        bf16x8 af = *(const bf16x8*)(A3w + c16 * 36 + q * 8);
#pragma unroll
        for (int t = 0; t < 8; ++t) {
          bf16x8 bfr = *(const bf16x8*)(W2s + (ch * 128 + t * 16 + c16) * 68 + sub * 32 + q * 8);
          zacc[t] = __builtin_amdgcn_mfma_f32_16x16x32_bf16(af, bfr, zacc[t], 0, 0, 0);
        }
      }
    }
  }

  // ---- epilogue: out = y + mlp + bm2 (all f32, no intermediate rounding)
#pragma unroll
  for (int r = 0; r < 4; ++r) {
    const long rowg = band * 16 + q * 4 + r;
#pragma unroll
    for (int t = 0; t < 8; ++t)
      out[rowg * 128 + t * 16 + c16] = yacc[t][r] + zacc[t][r] + bm2s[t * 16 + c16];
  }
}

extern "C" void kernel_launch(void* const* d_in, const int* in_sizes, int n_in,
                              void* d_out, int out_size, void* d_ws, size_t ws_size,
                              hipStream_t stream) {
  const float* x   = (const float*)d_in[0];
  const float* g1  = (const float*)d_in[1];
  const float* b1  = (const float*)d_in[2];
  // d_in[3]=Wq, [4]=bq, [7]=rpb dead (softmax over size-1 axis == 1)
  const float* Wkv = (const float*)d_in[5];
  const float* bkv = (const float*)d_in[6];
  const float* Wp  = (const float*)d_in[8];
  const float* bp  = (const float*)d_in[9];
  const float* g2  = (const float*)d_in[10];
  const float* b2  = (const float*)d_in[11];
  const float* W1  = (const float*)d_in[12];
  const float* bm1 = (const float*)d_in[13];
  const float* W2  = (const float*)d_in[14];
  const float* bm2 = (const float*)d_in[15];

  char* ws = (char*)d_ws;
  short* WcT  = (short*)(ws + 0);
  short* W1Ta = (short*)(ws + 100352);
  short* W2Ta = (short*)(ws + 167936);
  short* W1Tb = (short*)(ws + 237568);
  short* W2Tb = (short*)(ws + 305152);
  float* bc   = (float*)(ws + 374784);
  float* bm1c = (float*)(ws + 375296);

  prep<<<707, 256, 0, stream>>>(Wkv, bkv, Wp, bp, W1, W2, g1, b1, g2, b2, bm1,
                                WcT, W1Ta, W1Tb, W2Ta, W2Tb, bc, bm1c);
  fused<<<256, 1024, 0, stream>>>(x, WcT, bc, W1Ta, W2Ta, W1Tb, W2Tb,
                                  bm1c, bm2, (float*)d_out);
}